// Round 3
// baseline (8693.848 us; speedup 1.0000x reference)
//
#include <hip/hip_runtime.h>
#include <cstdint>

#define DD 64
#define HH 2
#define LAY 3
#define NN 50000
#define GG 128
#define EE 600000
#define NEE 300000
#define NAUG (NN + GG)            // 50128
#define E2 (EE + 2 * NN)          // 700000: loop edges start here
#define ESZ (E2 + NAUG)           // 750128
#define EPS_GEN_F 1e-7f
#define EPS_LN_F 1e-5f
#define SCAN_B 1024
#define NBLK ((NAUG + SCAN_B - 1) / SCAN_B)  // 49

// ---------------- device helpers ----------------

__device__ __forceinline__ float2 ld2(const float* p) {
  return *reinterpret_cast<const float2*>(p);
}
__device__ __forceinline__ void st2(float* p, float x, float y) {
  *reinterpret_cast<float2*>(p) = make_float2(x, y);
}

// butterfly sum within each 32-lane half (xor offsets never cross bit 5)
__device__ __forceinline__ float half_sum(float v) {
#pragma unroll
  for (int off = 16; off; off >>= 1) v += __shfl_xor(v, off);
  return v;  // identical on all lanes of the half
}

// e_aug[e][2*hl .. 2*hl+1] without materializing e_aug (hl in [0,32))
__device__ __forceinline__ float2 ea2_val(int e, int hl, const float* __restrict__ ea,
                                          const float* __restrict__ la) {
  if (e < EE) return ld2(ea + (size_t)e * DD + 2 * hl);
  if (e < E2) return make_float2((hl == 0) ? 1.0f : 0.0f, 0.0f);  // e_p rows
  return ld2(la + (size_t)(e - E2) * DD + 2 * hl);                // loop_attr rows
}

__device__ __forceinline__ int dst_of(int e, const int* __restrict__ ei1,
                                      const int* __restrict__ batch) {
  if (e < EE) return ei1[e];
  if (e < EE + NN) return batch[e - EE] + NN;  // u -> v
  if (e < E2) return e - (EE + NN);            // v -> u
  return e - E2;                               // loop
}
__device__ __forceinline__ int src_of(int e, const int* __restrict__ ei0,
                                      const int* __restrict__ batch) {
  if (e < EE) return ei0[e];
  if (e < EE + NN) return e - EE;
  if (e < E2) return batch[e - (EE + NN)] + NN;
  return e - E2;
}

// ---------------- CSR build ----------------

__global__ void hist_k(const int* __restrict__ ei1, const int* __restrict__ batch,
                       int* __restrict__ deg) {
  for (int e = blockIdx.x * blockDim.x + threadIdx.x; e < ESZ; e += gridDim.x * blockDim.x)
    atomicAdd(&deg[dst_of(e, ei1, batch)], 1);
}

// 3-phase exclusive scan of deg[NAUG] -> rowst[NAUG+1]
__global__ __launch_bounds__(SCAN_B) void scan1_k(const int* __restrict__ deg,
                                                  int* __restrict__ rowst,
                                                  int* __restrict__ bsum) {
  __shared__ int buf[SCAN_B];
  int i = blockIdx.x * SCAN_B + threadIdx.x;
  int v = (i < NAUG) ? deg[i] : 0;
  buf[threadIdx.x] = v;
  __syncthreads();
  int acc = v;
#pragma unroll
  for (int off = 1; off < SCAN_B; off <<= 1) {
    int t = (threadIdx.x >= off) ? buf[threadIdx.x - off] : 0;
    __syncthreads();
    buf[threadIdx.x] = acc = acc + t;
    __syncthreads();
  }
  if (i < NAUG) rowst[i] = acc - v;  // block-local exclusive
  if (threadIdx.x == SCAN_B - 1) bsum[blockIdx.x] = acc;
}

__global__ void scan2_k(const int* __restrict__ bsum, int* __restrict__ bpre,
                        int* __restrict__ rowst) {
  if (threadIdx.x == 0) {
    int run = 0;
    for (int b = 0; b < NBLK; b++) {
      bpre[b] = run;
      run += bsum[b];
    }
    rowst[NAUG] = run;  // == ESZ
  }
}

__global__ void scan3_k(int* __restrict__ rowst, const int* __restrict__ bpre) {
  int i = blockIdx.x * blockDim.x + threadIdx.x;
  if (i < NAUG) rowst[i] += bpre[i / SCAN_B];
}

__global__ void scatter_k(const int* __restrict__ ei0, const int* __restrict__ ei1,
                          const int* __restrict__ batch, const int* __restrict__ rowst,
                          int* __restrict__ fill, int* __restrict__ ceid,
                          int* __restrict__ csrc) {
  for (int e = blockIdx.x * blockDim.x + threadIdx.x; e < ESZ; e += gridDim.x * blockDim.x) {
    int dn = dst_of(e, ei1, batch);
    int pos = rowst[dn] + atomicAdd(&fill[dn], 1);
    ceid[pos] = e;
    csrc[pos] = src_of(e, ei0, batch);
  }
}

// graph start offsets from sorted batch
__global__ void gs_k(const int* __restrict__ batch, int* __restrict__ gs) {
  int i = blockIdx.x * blockDim.x + threadIdx.x;
  if (i >= NN) return;
  int b = batch[i];
  int prev = (i > 0) ? batch[i - 1] : -1;
  for (int g = prev + 1; g <= b; ++g) gs[g] = i;
  if (i == NN - 1)
    for (int g = b + 1; g <= GG; ++g) gs[g] = NN;
}

__global__ void hinit_k(const float4* __restrict__ x, const float4* __restrict__ cond,
                        float4* __restrict__ h) {
  for (int idx = blockIdx.x * blockDim.x + threadIdx.x; idx < NAUG * 16;
       idx += gridDim.x * blockDim.x)
    h[idx] = (idx < NN * 16) ? x[idx] : cond[idx - NN * 16];
}

// loop_attr[i] = sum over non-loop in-edges of e_base / max(cnt,1)
// two edges per wave (one per 32-lane half), float2 features
__global__ __launch_bounds__(256) void loopattr_k(const float* __restrict__ eattr,
                                                  const int* __restrict__ rowst,
                                                  const int* __restrict__ ceid,
                                                  float* __restrict__ la) {
  const int lane = threadIdx.x & 63;
  const int half = lane >> 5, hl = lane & 31;
  const int wv = threadIdx.x >> 6;
  for (int i = blockIdx.x * 4 + wv; i < NAUG; i += gridDim.x * 4) {
    int rs = rowst[i], re = rowst[i + 1];
    float ax = 0.f, ay = 0.f;
    int cnt = 0;
    for (int p = rs + half; p < re; p += 2) {
      int e = ceid[p];
      if (e >= E2) continue;  // skip self-loop rows
      cnt++;
      float2 ea = (e < EE) ? ld2(eattr + (size_t)e * DD + 2 * hl)
                           : make_float2((hl == 0) ? 1.0f : 0.0f, 0.0f);
      ax += ea.x;
      ay += ea.y;
    }
    ax += __shfl_xor(ax, 32);
    ay += __shfl_xor(ay, 32);
    cnt += __shfl_xor(cnt, 32);
    if (half == 0) {
      float inv = 1.0f / fmaxf((float)cnt, 1.0f);
      st2(la + (size_t)i * DD + 2 * hl, ax * inv, ay * inv);
    }
  }
}

// ---------------- LayerNorm (per graph) ----------------

__global__ __launch_bounds__(256) void ln_stats_k(const float* __restrict__ xin,
                                                  const int* __restrict__ gs,
                                                  float* __restrict__ mean,
                                                  float* __restrict__ rstd) {
  __shared__ float red[256];
  __shared__ float mu_s;
  int g = blockIdx.x;
  int s = gs[g], e = gs[g + 1];
  int cnt = e - s + 1;  // members + graph node
  int nel = cnt * DD;
  float norm = (float)nel;
  float acc = 0.f;
  for (int idx = threadIdx.x; idx < nel; idx += 256) {
    int loc = idx >> 6;
    int node = (loc < cnt - 1) ? (s + loc) : (NN + g);
    acc += xin[(size_t)node * DD + (idx & 63)];
  }
  red[threadIdx.x] = acc;
  __syncthreads();
  for (int o = 128; o; o >>= 1) {
    if (threadIdx.x < o) red[threadIdx.x] += red[threadIdx.x + o];
    __syncthreads();
  }
  if (threadIdx.x == 0) mu_s = red[0] / norm;
  __syncthreads();
  float mu = mu_s;
  acc = 0.f;
  for (int idx = threadIdx.x; idx < nel; idx += 256) {
    int loc = idx >> 6;
    int node = (loc < cnt - 1) ? (s + loc) : (NN + g);
    float d = xin[(size_t)node * DD + (idx & 63)] - mu;
    acc += d * d;
  }
  __syncthreads();
  red[threadIdx.x] = acc;
  __syncthreads();
  for (int o = 128; o; o >>= 1) {
    if (threadIdx.x < o) red[threadIdx.x] += red[threadIdx.x + o];
    __syncthreads();
  }
  if (threadIdx.x == 0) {
    mean[g] = mu;
    rstd[g] = rsqrtf(red[0] / norm + EPS_LN_F);
  }
}

__global__ void ln_apply_k(const float* __restrict__ xin, const int* __restrict__ batch,
                           const float* __restrict__ mean, const float* __restrict__ rstd,
                           float* __restrict__ o1, float* __restrict__ o2) {
  for (int idx = blockIdx.x * blockDim.x + threadIdx.x; idx < NAUG * 32;
       idx += gridDim.x * blockDim.x) {
    int i = idx >> 5, d2 = idx & 31;
    int g = (i < NN) ? batch[i] : (i - NN);
    float mu = mean[g], rs = rstd[g];
    float2 v = ld2(xin + (size_t)i * DD + 2 * d2);
    float vx = (v.x - mu) * rs, vy = (v.y - mu) * rs;
    st2(o1 + (size_t)i * DD + 2 * d2, vx, vy);
    if (o2) st2(o2 + (size_t)i * 128 + 2 * d2, vx, vy);  // cat[:, :64]
  }
}

// ---------------- gen_conv node aggregation ----------------
// gin[i] = sum_in relu(hn[src]+e_aug) + deg*eps + hn[i]
// two edges per wave (one per half), float2 features
__global__ __launch_bounds__(256) void gen_node_k(const float* __restrict__ hn,
                                                  const int* __restrict__ rowst,
                                                  const int* __restrict__ ceid,
                                                  const int* __restrict__ csrc,
                                                  const float* __restrict__ eattr,
                                                  const float* __restrict__ la,
                                                  float* __restrict__ gin) {
  const int lane = threadIdx.x & 63;
  const int half = lane >> 5, hl = lane & 31;
  const int wv = threadIdx.x >> 6;
  for (int i = blockIdx.x * 4 + wv; i < NAUG; i += gridDim.x * 4) {
    int rs = rowst[i], re = rowst[i + 1];
    float ax = 0.f, ay = 0.f;
    for (int p = rs + half; p < re; p += 2) {
      int j = csrc[p], e = ceid[p];
      float2 ea = ea2_val(e, hl, eattr, la);
      float2 hv = ld2(hn + (size_t)j * DD + 2 * hl);
      ax += fmaxf(hv.x + ea.x, 0.f);
      ay += fmaxf(hv.y + ea.y, 0.f);
    }
    ax += __shfl_xor(ax, 32);
    ay += __shfl_xor(ay, 32);
    if (half == 0) {
      float2 hme = ld2(hn + (size_t)i * DD + 2 * hl);
      float epsterm = (float)(re - rs) * EPS_GEN_F;
      st2(gin + (size_t)i * DD + 2 * hl, ax + epsterm + hme.x, ay + epsterm + hme.y);
    }
  }
}

// ---------------- generic fp32 GEMM: C[:, coff:coff+OUT] (+)= act(A@W + b) ----------------
template <int IN, int OUT, int ACT, bool ACCUM>
__global__ __launch_bounds__(256) void gemm_k(const float* __restrict__ A,
                                              const float* __restrict__ W,
                                              const float* __restrict__ bias,
                                              float* __restrict__ C, int ldc, int coff) {
  __shared__ float sW[IN * OUT];
  for (int idx = threadIdx.x; idx < IN * OUT; idx += 256) sW[idx] = W[idx];
  __syncthreads();
  const int lane = threadIdx.x & 63;
  const int wv = threadIdx.x >> 6;
  constexpr int AR = IN / 64, CR = OUT / 64;
  for (int row = blockIdx.x * 4 + wv; row < NAUG; row += gridDim.x * 4) {
    float a[AR];
#pragma unroll
    for (int r = 0; r < AR; r++) a[r] = A[(size_t)row * IN + r * 64 + lane];
    float acc[CR];
#pragma unroll
    for (int c = 0; c < CR; c++) acc[c] = bias ? bias[c * 64 + lane] : 0.f;
#pragma unroll
    for (int r = 0; r < AR; r++) {
#pragma unroll
      for (int kk = 0; kk < 64; kk++) {
        float av = __shfl(a[r], kk);
#pragma unroll
        for (int c = 0; c < CR; c++) acc[c] += av * sW[(r * 64 + kk) * OUT + c * 64 + lane];
      }
    }
#pragma unroll
    for (int c = 0; c < CR; c++) {
      float o = acc[c];
      if (ACT == 1) o = (o > 0.f) ? o : 0.01f * o;
      float* p = C + (size_t)row * ldc + coff + c * 64 + lane;
      if (ACCUM)
        *p += o;
      else
        *p = o;
    }
  }
}

// qe[i,h,c] = sum_d q[i,h,d] * ew[c, h*64+d]
__global__ __launch_bounds__(256) void qe_k(const float* __restrict__ q,
                                            const float* __restrict__ ew,
                                            float* __restrict__ qe) {
  __shared__ float sT[128 * 64];  // sT[k][c] = ew[c][k]
  for (int idx = threadIdx.x; idx < 64 * 128; idx += 256) {
    int c = idx >> 7, kk = idx & 127;
    sT[kk * 64 + c] = ew[idx];
  }
  __syncthreads();
  const int lane = threadIdx.x & 63;
  const int wv = threadIdx.x >> 6;
  for (int i = blockIdx.x * 4 + wv; i < NAUG; i += gridDim.x * 4) {
    float a0 = q[(size_t)i * 128 + lane];
    float a1 = q[(size_t)i * 128 + 64 + lane];
    float acc0 = 0.f, acc1 = 0.f;
#pragma unroll
    for (int d = 0; d < 64; d++) {
      float v0 = __shfl(a0, d), v1 = __shfl(a1, d);
      acc0 += v0 * sT[d * 64 + lane];
      acc1 += v1 * sT[(64 + d) * 64 + lane];
    }
    qe[(size_t)i * 128 + lane] = acc0;
    qe[(size_t)i * 128 + 64 + lane] = acc1;
  }
}

// block-diag weight: Wbd[k,o] = (k/64==o/64) ? ew[k%64, o] : 0
__global__ void wbd_k(const float* __restrict__ ew, float* __restrict__ wbd) {
  int idx = blockIdx.x * 256 + threadIdx.x;
  if (idx >= 128 * 128) return;
  int k = idx >> 7, o = idx & 127;
  wbd[idx] = ((k >> 6) == (o >> 6)) ? ew[(k & 63) * 128 + o] : 0.f;
}

// ---------------- attention: single-pass online softmax ----------------
// Lane l owns elements {2l, 2l+1} of the 128-wide rows -> head 0 lives in
// lanes 0..31, head 1 in lanes 32..63. Dot-product reduces within each half
// (5-step butterfly); softmax state (m,s) is per-half-uniform; no cross-half
// exchange needed. edge_attr read exactly once.
__global__ __launch_bounds__(256) void attn_k(
    const float* __restrict__ q, const float* __restrict__ k, const float* __restrict__ v,
    const float* __restrict__ qe, const int* __restrict__ rowst, const int* __restrict__ ceid,
    const int* __restrict__ csrc, const float* __restrict__ eattr, const float* __restrict__ la,
    float* __restrict__ outv, float* __restrict__ z) {
  const int lane = threadIdx.x & 63;
  const int hl = lane & 31;
  const int wv = threadIdx.x >> 6;
  for (int i = blockIdx.x * 4 + wv; i < NAUG; i += gridDim.x * 4) {
    const int rs = rowst[i], re = rowst[i + 1];
    float2 q2 = ld2(q + (size_t)i * 128 + 2 * lane);
    float2 e2 = ld2(qe + (size_t)i * 128 + 2 * lane);
    float m = -1e30f, s = 0.f;
    float avx = 0.f, avy = 0.f, azx = 0.f, azy = 0.f;
    for (int p = rs; p < re; ++p) {
      int j = csrc[p], e = ceid[p];
      float2 ea = ea2_val(e, hl, eattr, la);
      float2 k2 = ld2(k + (size_t)j * 128 + 2 * lane);
      float2 v2 = ld2(v + (size_t)j * 128 + 2 * lane);
      float part = q2.x * k2.x + q2.y * k2.y + e2.x * ea.x + e2.y * ea.y;
      float a = half_sum(part) * 0.125f;  // alpha for this half's head
      float nm = fmaxf(m, a);
      float c = __expf(m - nm), w = __expf(a - nm);
      m = nm;
      s = s * c + w;
      avx = avx * c + w * v2.x;
      avy = avy * c + w * v2.y;
      azx = azx * c + w * ea.x;
      azy = azy * c + w * ea.y;
    }
    float inv = 1.0f / (s + 1e-16f);
    st2(outv + (size_t)i * 128 + 2 * lane, avx * inv, avy * inv);
    st2(z + (size_t)i * 128 + 2 * lane, azx * inv, azy * inv);
  }
}

// ---------------- outputs ----------------

__global__ void nemb_k(const float4* __restrict__ h, float4* __restrict__ out) {
  for (int idx = blockIdx.x * blockDim.x + threadIdx.x; idx < NN * 16;
       idx += gridDim.x * blockDim.x)
    out[idx] = h[idx];
}

__global__ __launch_bounds__(256) void glob_k(const float* __restrict__ h,
                                              const int* __restrict__ gs,
                                              float* __restrict__ out) {
  __shared__ float part[4][64];
  int g = blockIdx.x;
  int d = threadIdx.x & 63, sub = threadIdx.x >> 6;
  int s = gs[g], e = gs[g + 1];
  float acc = 0.f;
  for (int node = s + sub; node < e; node += 4) acc += h[(size_t)node * DD + d];
  part[sub][d] = acc;
  __syncthreads();
  if (sub == 0) {
    float t = part[0][d] + part[1][d] + part[2][d] + part[3][d];
    t /= fmaxf((float)(e - s), 1.0f);
    t += h[(size_t)(NN + g) * DD + d];
    out[(size_t)NN * DD + (size_t)g * DD + d] = t;
  }
}

__global__ void ne_k(const float4* __restrict__ h4, const int* __restrict__ a,
                     const int* __restrict__ b, float4* __restrict__ out4) {
  const size_t base = (size_t)(NN + GG) * 16;
  for (size_t idx = blockIdx.x * blockDim.x + threadIdx.x; idx < (size_t)NEE * 16;
       idx += (size_t)gridDim.x * blockDim.x) {
    int r = (int)(idx >> 4), c = (int)(idx & 15);
    float4 va = h4[(size_t)a[r] * 16 + c];
    float4 vb = h4[(size_t)b[r] * 16 + c];
    out4[base + idx] = make_float4(va.x + vb.x, va.y + vb.y, va.z + vb.z, va.w + vb.w);
  }
}

// ---------------- host ----------------

extern "C" void kernel_launch(void* const* d_in, const int* in_sizes, int n_in, void* d_out,
                              int out_size, void* d_ws, size_t ws_size, hipStream_t stream) {
  const float* x = (const float*)d_in[0];
  const float* cond = (const float*)d_in[1];
  const float* eattr = (const float*)d_in[2];
  const int* eidx = (const int*)d_in[3];
  const int* neidx = (const int*)d_in[4];
  const int* batch = (const int*)d_in[5];
  const float* gen_w = (const float*)d_in[6];
  const float* gen_b = (const float*)d_in[7];
  const float* q_w = (const float*)d_in[8];
  const float* q_b = (const float*)d_in[9];
  const float* k_w = (const float*)d_in[10];
  const float* k_b = (const float*)d_in[11];
  const float* v_w = (const float*)d_in[12];
  const float* v_b = (const float*)d_in[13];
  const float* e_w = (const float*)d_in[14];
  const float* skip_w = (const float*)d_in[15];
  const float* skip_b = (const float*)d_in[16];
  const float* lin_w = (const float*)d_in[17];
  const float* lin_b = (const float*)d_in[18];
  const float* ff_w1 = (const float*)d_in[19];
  const float* ff_b1 = (const float*)d_in[20];
  const float* ff_w2 = (const float*)d_in[21];
  const float* ff_b2 = (const float*)d_in[22];
  float* out = (float*)d_out;

  size_t off = 0;
  auto alloc = [&](size_t bytes) -> void* {
    void* p = (char*)d_ws + off;
    off += (bytes + 255) & ~(size_t)255;
    return p;
  };
  float* h = (float*)alloc((size_t)NAUG * 64 * 4);
  float* la = (float*)alloc((size_t)NAUG * 64 * 4);
  float* hn = (float*)alloc((size_t)NAUG * 64 * 4);
  float* cat = (float*)alloc((size_t)NAUG * 128 * 4);
  float* qb_ = (float*)alloc((size_t)NAUG * 128 * 4);
  float* kb_ = (float*)alloc((size_t)NAUG * 128 * 4);
  float* vb_ = (float*)alloc((size_t)NAUG * 128 * 4);  // vb_+qeb contiguous -> ffmid (256 wide)
  float* qeb = (float*)alloc((size_t)NAUG * 128 * 4);
  float* ob = (float*)alloc((size_t)NAUG * 128 * 4);
  float* zb = (float*)alloc((size_t)NAUG * 128 * 4);
  int* deg = (int*)alloc((size_t)NAUG * 4);
  int* fill = (int*)alloc((size_t)NAUG * 4);
  int* rowst = (int*)alloc((size_t)(NAUG + 1) * 4);
  int* ceid = (int*)alloc((size_t)ESZ * 4);
  int* csrc = (int*)alloc((size_t)ESZ * 4);
  int* gs = (int*)alloc((size_t)(GG + 1) * 4);
  int* bsum = (int*)alloc((size_t)NBLK * 4);
  int* bpre = (int*)alloc((size_t)(NBLK + 1) * 4);
  float* mean = (float*)alloc(GG * 4);
  float* rstd = (float*)alloc(GG * 4);
  float* wbd = (float*)alloc(128 * 128 * 4);
  (void)ws_size;

  // ---- graph preprocessing (per launch; no state carried) ----
  hipMemsetAsync(deg, 0, (size_t)NAUG * 4, stream);
  hist_k<<<1024, 256, 0, stream>>>(eidx + EE, batch, deg);
  scan1_k<<<NBLK, SCAN_B, 0, stream>>>(deg, rowst, bsum);
  scan2_k<<<1, 64, 0, stream>>>(bsum, bpre, rowst);
  scan3_k<<<(NAUG + 255) / 256, 256, 0, stream>>>(rowst, bpre);
  hipMemsetAsync(fill, 0, (size_t)NAUG * 4, stream);
  scatter_k<<<1024, 256, 0, stream>>>(eidx, eidx + EE, batch, rowst, fill, ceid, csrc);
  gs_k<<<(NN + 255) / 256, 256, 0, stream>>>(batch, gs);
  hinit_k<<<2048, 256, 0, stream>>>((const float4*)x, (const float4*)cond, (float4*)h);
  loopattr_k<<<2048, 256, 0, stream>>>(eattr, rowst, ceid, la);

  for (int l = 0; l < LAY; l++) {
    const float* gw = gen_w + (size_t)l * 64 * 64;
    const float* gb = gen_b + (size_t)l * 64;
    const float* qw = q_w + (size_t)l * 128 * 128;
    const float* qbia = q_b + (size_t)l * 128;
    const float* kw = k_w + (size_t)l * 128 * 128;
    const float* kbia = k_b + (size_t)l * 128;
    const float* vw = v_w + (size_t)l * 128 * 128;
    const float* vbia = v_b + (size_t)l * 128;
    const float* ew = e_w + (size_t)l * 64 * 128;
    const float* sw = skip_w + (size_t)l * 128 * 128;
    const float* sb = skip_b + (size_t)l * 128;
    const float* lw = lin_w + (size_t)l * 128 * 64;
    const float* lb = lin_b + (size_t)l * 64;
    const float* f1w = ff_w1 + (size_t)l * 64 * 256;
    const float* f1b = ff_b1 + (size_t)l * 256;
    const float* f2w = ff_w2 + (size_t)l * 256 * 64;
    const float* f2b = ff_b2 + (size_t)l * 64;

    ln_stats_k<<<GG, 256, 0, stream>>>(h, gs, mean, rstd);
    ln_apply_k<<<2048, 256, 0, stream>>>(h, batch, mean, rstd, hn, cat);  // hn + cat[:,:64]
    gen_node_k<<<2048, 256, 0, stream>>>(hn, rowst, ceid, csrc, eattr, la, zb);  // gin -> zb
    gemm_k<64, 64, 0, false><<<1024, 256, 0, stream>>>(zb, gw, gb, cat, 128, 64);  // cat[:,64:]
    gemm_k<128, 128, 0, false><<<1024, 256, 0, stream>>>(cat, qw, qbia, qb_, 128, 0);
    gemm_k<128, 128, 0, false><<<1024, 256, 0, stream>>>(cat, kw, kbia, kb_, 128, 0);
    gemm_k<128, 128, 0, false><<<1024, 256, 0, stream>>>(cat, vw, vbia, vb_, 128, 0);
    qe_k<<<2048, 256, 0, stream>>>(qb_, ew, qeb);
    attn_k<<<2048, 256, 0, stream>>>(qb_, kb_, vb_, qeb, rowst, ceid, csrc, eattr, la, ob, zb);
    wbd_k<<<64, 256, 0, stream>>>(ew, wbd);
    gemm_k<128, 128, 0, true><<<1024, 256, 0, stream>>>(cat, sw, sb, ob, 128, 0);   // + skip
    gemm_k<128, 128, 0, true><<<1024, 256, 0, stream>>>(zb, wbd, nullptr, ob, 128, 0);  // + z@ew
    gemm_k<128, 64, 0, false><<<1024, 256, 0, stream>>>(ob, lw, lb, hn, 64, 0);  // lh -> hn
    ln_stats_k<<<GG, 256, 0, stream>>>(hn, gs, mean, rstd);
    ln_apply_k<<<2048, 256, 0, stream>>>(hn, batch, mean, rstd, kb_, nullptr);  // ln2 -> kb_
    gemm_k<64, 256, 1, false><<<1024, 256, 0, stream>>>(kb_, f1w, f1b, vb_, 256, 0);  // ffmid
    gemm_k<256, 64, 0, true><<<1024, 256, 0, stream>>>(vb_, f2w, f2b, h, 64, 0);  // h += ff
  }

  nemb_k<<<2048, 256, 0, stream>>>((const float4*)h, (float4*)out);
  glob_k<<<GG, 256, 0, stream>>>(h, gs, out);
  ne_k<<<8192, 256, 0, stream>>>((const float4*)h, neidx, neidx + NEE, (float4*)out);
}